// Round 2
// baseline (237.836 us; speedup 1.0000x reference)
//
#include <hip/hip_runtime.h>

#define NN 16
#define DD 64
#define SS 32
#define MM 48
// output element (n,s,i,j,k) at ((n*SS+s)*MM + i)*MM*MM + j*MM + k

typedef float floatx4 __attribute__((ext_vector_type(4)));

__global__ __launch_bounds__(576, 1) void eq1to3_kernel(
    const float* __restrict__ x,      // (N, D, M)
    const float* __restrict__ coefs,  // (D, S, 4)
    const float* __restrict__ bias,   // (1, S, 1, 1, 1) -> [S]
    float* __restrict__ out)          // (N, S, M, M, M)
{
    __shared__ float t_lds[4][MM];    // t[b][m] for this (n,s)

    const int ns = blockIdx.x;        // 0..511
    const int n  = ns / SS;
    const int s  = ns % SS;
    const int tid = threadIdx.x;      // 0..575

    // ---- Phase 1: t[b][m] = sum_d coefs[d,s,b] * x[n,d,m]  (tiny) ----
    if (tid < 4 * MM) {
        const int m = tid % MM;
        const int b = tid / MM;
        const float* xp = x + (size_t)n * DD * MM + m;
        const float* cp = coefs + s * 4 + b;
        float acc = 0.f;
        #pragma unroll 8
        for (int d = 0; d < DD; ++d) {
            acc += cp[(size_t)d * SS * 4] * xp[(size_t)d * MM];
        }
        t_lds[b][m] = acc;
    }
    __syncthreads();

    // ---- Phase 2: broadcast-expand + non-temporal streaming store ----
    // thread owns (j, k4): j = row in dim-j, k4 = which float4 along k.
    // Per i-plane the whole block stores 48*48 floats = 9216 B contiguous.
    const int j  = tid / (MM / 4);    // 0..47
    const int k4 = tid % (MM / 4);    // 0..11

    const float bs  = bias[s];
    const float t1j = t_lds[1][j];
    floatx4 base;
    base.x = t_lds[2][4 * k4 + 0] + t1j + bs;
    base.y = t_lds[2][4 * k4 + 1] + t1j + bs;
    base.z = t_lds[2][4 * k4 + 2] + t1j + bs;
    base.w = t_lds[2][4 * k4 + 3] + t1j + bs;

    floatx4* outp = (floatx4*)(out + (size_t)ns * MM * MM * MM + j * MM + 4 * k4);
    const int plane4 = MM * MM / 4;   // 576 float4 per i-plane

    // i < j planes
    #pragma unroll 2
    for (int i = 0; i < j; ++i) {
        const float t0i = t_lds[0][i];
        floatx4 v = base + t0i;
        __builtin_nontemporal_store(v, outp + (size_t)i * plane4);
    }

    // i == j plane: superdiagonal fixup (only the thread whose k-quad holds k==j)
    {
        const float t0i = t_lds[0][j];
        floatx4 v = base + t0i;
        if ((j >> 2) == k4) {
            const float t3j = t_lds[3][j];
            v[j & 3] += t3j;
        }
        __builtin_nontemporal_store(v, outp + (size_t)j * plane4);
    }

    // i > j planes
    #pragma unroll 2
    for (int i = j + 1; i < MM; ++i) {
        const float t0i = t_lds[0][i];
        floatx4 v = base + t0i;
        __builtin_nontemporal_store(v, outp + (size_t)i * plane4);
    }
}

extern "C" void kernel_launch(void* const* d_in, const int* in_sizes, int n_in,
                              void* d_out, int out_size, void* d_ws, size_t ws_size,
                              hipStream_t stream) {
    const float* x     = (const float*)d_in[0];
    const float* coefs = (const float*)d_in[1];
    const float* bias  = (const float*)d_in[2];
    float* out = (float*)d_out;

    eq1to3_kernel<<<dim3(NN * SS), dim3(576), 0, stream>>>(x, coefs, bias, out);
}